// Round 4
// baseline (213.374 us; speedup 1.0000x reference)
//
#include <hip/hip_runtime.h>
#include <hip/hip_bf16.h>
#include <hip/hip_cooperative_groups.h>

namespace cg = cooperative_groups;

// ContrastiveLoss: z (8192x1024 fp32) -> scalar
//   zn = z / max(||z||,eps); S = zn@zn^T; diag=MASK; /T; nll = -S[i,i^4096] + lse(S[i,:]); mean
// R11: single COOPERATIVE kernel fusing normalize / tile-GEMM / final reduce.
// Rationale: across R7/R9/R10, total - k_tile ~= 68us constant (launch/gap
// overhead of the 3-kernel chain; hand-computed phase1+3 work is only ~10us).
// 256 blocks x 512 thr x 128KB LDS = 1 block/CU, fully co-resident ->
// grid.sync() legal. Phase 2 is the PROVEN R7 body (fp8 e4m3 16x16x32 MFMA,
// BK=128, 2-buffer, gload_lds direct, 0-conflict swizzle, 24.7us/tile);
// tiles handed out by dynamic atomic ticket (zeroed in phase 1).
// R10 lesson: counted-vmcnt 4-buffer pipeline REGRESSED (85.9 vs 74us) -
// R7's top-of-stage prefetch already covers HBM latency; keep R7 schedule.

#define N 8192
#define D 1024
#define INV_T 14.285714285714286f
#define NTILES 528
#define NBLK 256
#define ACC_SCALE (INV_T / 1024.0f)  // undo fp8 x32 scaling on both operands

typedef float f32x4 __attribute__((ext_vector_type(4)));
typedef long lx2 __attribute__((ext_vector_type(2)));

__device__ inline void gload16(const void* g, void* l) {
  __builtin_amdgcn_global_load_lds(
      (const __attribute__((address_space(1))) void*)g,
      (__attribute__((address_space(3))) void*)l, 16, 0, 0);
}

__global__ __launch_bounds__(512, 2) void k_fused(
    const float* __restrict__ z, unsigned char* __restrict__ zn8,
    float* __restrict__ rowsum, float* __restrict__ pos,
    float* __restrict__ out, int* __restrict__ ticket) {
  extern __shared__ __align__(16) char smem[];  // 131072 dynamic
  const int tid = threadIdx.x;
  const int bid = blockIdx.x;
  const int w = tid >> 6, l = tid & 63;

  // ---------------- phase 1: normalize rows, cast fp8, zero rowsum/ticket ----
  if (bid == 0 && tid == 0) *ticket = 0;
  {
    const int gid = bid * 512 + tid;
    if (gid < N) rowsum[gid] = 0.0f;
#pragma unroll
    for (int rr = 0; rr < 4; ++rr) {
      const int row = (bid * 8 + w) * 4 + rr;  // 256 blk * 8 waves * 4 rows = 8192
      const float4* zr = (const float4*)(z + (size_t)row * D);
      float4 v[4];
      float ss = 0.f;
#pragma unroll
      for (int j = 0; j < 4; ++j) {
        v[j] = zr[l + 64 * j];  // coalesced 16B/lane
        ss += v[j].x * v[j].x + v[j].y * v[j].y + v[j].z * v[j].z + v[j].w * v[j].w;
      }
#pragma unroll
      for (int off = 32; off > 0; off >>= 1) ss += __shfl_xor(ss, off, 64);
      const float sc = 32.0f / fmaxf(sqrtf(ss), 1e-8f);  // undone by ACC_SCALE
      int* orow = (int*)(zn8 + (size_t)row * D);
#pragma unroll
      for (int j = 0; j < 4; ++j) {
        int p = __builtin_amdgcn_cvt_pk_fp8_f32(v[j].x * sc, v[j].y * sc, 0, false);
        p = __builtin_amdgcn_cvt_pk_fp8_f32(v[j].z * sc, v[j].w * sc, p, true);
        orow[l + 64 * j] = p;
      }
    }
  }
  cg::this_grid().sync();

  // ---------------- phase 2: 256x256 lower-tri tiles, dynamic ticket --------
  const int wr = w >> 1, wc = w & 1;
  const int m = l & 15, kg = l >> 4;

  // staging map: per matrix per stage 2048 slots x 16B (256 rows x 8 chunks).
  // phys slot s -> row s>>3; phys chunk s&7 holds logical chunk (s&7)^(row&7).
  int srow[4], scol[4];
#pragma unroll
  for (int j = 0; j < 4; ++j) {
    int s = j * 512 + tid;
    int r = s >> 3;
    srow[j] = r;
    scol[j] = (s & 7) ^ (r & 7);
  }
  // fragment reads: logical chunks kg, kg+4 (K-permuted; A/B identical)
  const int csw0 = (kg ^ (m & 7)) * 16;
  const int csw1 = ((kg + 4) ^ (m & 7)) * 16;

  __shared__ int s_t;
  for (;;) {
    if (tid == 0) s_t = atomicAdd(ticket, 1);
    __syncthreads();
    const int b = s_t;
    if (b >= NTILES) break;

    // decode b -> lower-triangle (tr, tc), tr >= tc
    int tr = (int)((sqrtf(8.0f * (float)b + 1.0f) - 1.0f) * 0.5f);
    if (tr * (tr + 1) / 2 > b) --tr;
    if ((tr + 1) * (tr + 2) / 2 <= b) ++tr;
    const int tc = b - tr * (tr + 1) / 2;
    const bool diag = (tr == tc);
    const int rowA0 = tr * 256, colB0 = tc * 256;

    f32x4 acc[4][8] = {};

    // prologue: stage kt=0 into buffer 0
    {
      char* ab = smem;
      char* bb = smem + 32768;
#pragma unroll
      for (int j = 0; j < 4; ++j) {
        const int s = j * 512 + tid;
        gload16((const char*)zn8 + ((size_t)(rowA0 + srow[j]) * D + scol[j] * 16), ab + s * 16);
      }
      if (!diag) {
#pragma unroll
        for (int j = 0; j < 4; ++j) {
          const int s = j * 512 + tid;
          gload16((const char*)zn8 + ((size_t)(colB0 + srow[j]) * D + scol[j] * 16), bb + s * 16);
        }
      }
    }
    __syncthreads();

    for (int kt = 0; kt < 8; ++kt) {
      if (kt < 7) {  // async prefetch kt+1 into other buffer; overlaps MFMA
        const size_t kb = (size_t)(kt + 1) * 128;
        char* ab = smem + ((kt + 1) & 1) * 65536;
#pragma unroll
        for (int j = 0; j < 4; ++j) {
          const int s = j * 512 + tid;
          gload16((const char*)zn8 + ((size_t)(rowA0 + srow[j]) * D + kb + scol[j] * 16), ab + s * 16);
        }
        if (!diag) {
          char* bb = ab + 32768;
#pragma unroll
          for (int j = 0; j < 4; ++j) {
            const int s = j * 512 + tid;
            gload16((const char*)zn8 + ((size_t)(colB0 + srow[j]) * D + kb + scol[j] * 16), bb + s * 16);
          }
        }
      }
      const char* ab = smem + (kt & 1) * 65536;
      const char* bb = diag ? ab : (ab + 32768);

      lx2 a0[4], a1[4];
#pragma unroll
      for (int mt = 0; mt < 4; ++mt) {
        const char* rp = ab + (wr * 64 + mt * 16 + m) * 128;
        a0[mt] = *(const lx2*)(rp + csw0);
        a1[mt] = *(const lx2*)(rp + csw1);
      }
#pragma unroll
      for (int nt = 0; nt < 8; ++nt) {
        const char* rp = bb + (wc * 128 + nt * 16 + m) * 128;
        const lx2 b0 = *(const lx2*)(rp + csw0);
        const lx2 b1 = *(const lx2*)(rp + csw1);
#pragma unroll
        for (int mt = 0; mt < 4; ++mt) {
          acc[mt][nt] = __builtin_amdgcn_mfma_f32_16x16x32_fp8_fp8(a0[mt].x, b0.x, acc[mt][nt], 0, 0, 0);
          acc[mt][nt] = __builtin_amdgcn_mfma_f32_16x16x32_fp8_fp8(a0[mt].y, b0.y, acc[mt][nt], 0, 0, 0);
          acc[mt][nt] = __builtin_amdgcn_mfma_f32_16x16x32_fp8_fp8(a1[mt].x, b1.x, acc[mt][nt], 0, 0, 0);
          acc[mt][nt] = __builtin_amdgcn_mfma_f32_16x16x32_fp8_fp8(a1[mt].y, b1.y, acc[mt][nt], 0, 0, 0);
        }
      }
      __syncthreads();  // drains prefetch (vmcnt) + guards buffer reuse
    }

    // Epilogue. C/D layout: col=l&15, row=(l>>4)*4+reg.
    const int quad = l >> 4;
    const int col = l & 15;
    float cs[8] = {0.f, 0.f, 0.f, 0.f, 0.f, 0.f, 0.f, 0.f};
#pragma unroll
    for (int mt = 0; mt < 4; ++mt) {
      float rs[4] = {0.f, 0.f, 0.f, 0.f};
#pragma unroll
      for (int nt = 0; nt < 8; ++nt) {
        const int gcol = colB0 + wc * 128 + nt * 16 + col;
#pragma unroll
        for (int r = 0; r < 4; ++r) {
          const int grow = rowA0 + wr * 64 + mt * 16 + quad * 4 + r;
          const float t = acc[mt][nt][r] * ACC_SCALE;
          if (gcol == (grow ^ (N / 2))) {  // pos pair; never in diag tiles
            pos[grow] = t;
            pos[gcol] = t;  // S symmetric
          }
          const float e = (gcol == grow) ? 0.0f : __expf(t - INV_T);
          rs[r] += e;
          cs[nt] += e;
        }
      }
#pragma unroll
      for (int off = 1; off < 16; off <<= 1) {
#pragma unroll
        for (int r = 0; r < 4; ++r) rs[r] += __shfl_xor(rs[r], off, 64);
      }
      if (col == 0) {
#pragma unroll
        for (int r = 0; r < 4; ++r)
          atomicAdd(&rowsum[rowA0 + wr * 64 + mt * 16 + quad * 4 + r], rs[r]);
      }
    }
    if (!diag) {  // col sums = row-sums for block tc rows (symmetry)
#pragma unroll
      for (int nt = 0; nt < 8; ++nt) {
        cs[nt] += __shfl_xor(cs[nt], 16, 64);
        cs[nt] += __shfl_xor(cs[nt], 32, 64);
      }
      if (l < 16) {
#pragma unroll
        for (int nt = 0; nt < 8; ++nt)
          atomicAdd(&rowsum[colB0 + wc * 128 + nt * 16 + l], cs[nt]);
      }
    }
  }
  cg::this_grid().sync();

  // ---------------- phase 3: block 0 reduces ---------------------------------
  if (bid == 0) {
    float s = 0.f;
    for (int i = tid; i < N; i += 512) s += INV_T + __logf(rowsum[i]) - pos[i];
#pragma unroll
    for (int off = 32; off > 0; off >>= 1) s += __shfl_down(s, off, 64);
    __shared__ float red[8];
    if ((tid & 63) == 0) red[tid >> 6] = s;
    __syncthreads();
    if (tid == 0) {
      float tot = 0.f;
#pragma unroll
      for (int j = 0; j < 8; ++j) tot += red[j];
      out[0] = tot * (1.0f / N);
    }
  }
}

extern "C" void kernel_launch(void* const* d_in, const int* in_sizes, int n_in,
                              void* d_out, int out_size, void* d_ws, size_t ws_size,
                              hipStream_t stream) {
  const float* z = (const float*)d_in[0];
  float* out = (float*)d_out;
  char* ws = (char*)d_ws;
  unsigned char* zn8 = (unsigned char*)ws;                       // 8 MiB fp8
  float* rowsum = (float*)(ws + (size_t)N * D);                  // 32 KiB
  float* pos = (float*)(ws + (size_t)N * D + (size_t)N * 4);     // 32 KiB
  int* ticket = (int*)(ws + (size_t)N * D + (size_t)N * 8);      // 4 B

  static bool attr_set = false;
  if (!attr_set) {  // host-side attribute, idempotent, not a stream op
    hipFuncSetAttribute((const void*)k_fused,
                        hipFuncAttributeMaxDynamicSharedMemorySize, 131072);
    attr_set = true;
  }

  void* args[] = {(void*)&z, (void*)&zn8, (void*)&rowsum,
                  (void*)&pos, (void*)&out, (void*)&ticket};
  hipLaunchCooperativeKernel((const void*)k_fused, dim3(NBLK), dim3(512),
                             args, 131072, stream);
}

// Round 5
// 161.953 us; speedup vs baseline: 1.3175x; 1.3175x over previous
//
#include <hip/hip_runtime.h>
#include <hip/hip_bf16.h>

// ContrastiveLoss: z (8192x1024 fp32) -> scalar
//   zn = z / max(||z||,eps); S = zn@zn^T; diag=MASK; /T; nll = -S[i,i^4096] + lse(S[i,:]); mean
// R12: 3-kernel structure (R11 proved the ~71us gap is FIXED harness overhead:
// single-kernel run had the identical gap; fusing/cooperative = dead end, and
// the persistent-ticket loop was 2x slower). k_tile re-tiled 256x256->128x128:
//   acc[2][4]=32 regs (vs 128) -> total ~110 regs -> 4 waves/SIMD legal;
//   LDS 32KB/stage double-buffered = 64KB -> 2 blocks/CU co-resident.
// Kills the two measured losses of R7: 528-tile/256-CU 3-round quantization
// (31% tail waste -> 2080/512 = 4.06 rounds, 1.5%) and un-hidden barrier
// drains at 1 block/CU (co-resident block's MFMA fills them, m114).
// Numerics/layout proven in R7: fp8 e4m3 x32 scaling, 16x16x32 MFMA,
// 128B-row LDS with chunk^(row&7) swizzle (0 conflicts measured), K-permuted
// b128 fragment reads (chunks kg, kg+4), same epilogue.
// R9 lesson guarded: spill signature = WRITE_SIZE >> 6MB; acc is only 32 regs
// here so launch_bounds(512,4) should fit without spill.

#define N 8192
#define D 1024
#define INV_T 14.285714285714286f
#define NTILES 2080  // 64*65/2 lower-tri over 128-row tile grid
#define ACC_SCALE (INV_T / 1024.0f)  // undo fp8 x32 scaling on both operands

typedef float f32x4 __attribute__((ext_vector_type(4)));
typedef long lx2 __attribute__((ext_vector_type(2)));

__device__ inline void gload16(const void* g, void* l) {
  __builtin_amdgcn_global_load_lds(
      (const __attribute__((address_space(1))) void*)g,
      (__attribute__((address_space(3))) void*)l, 16, 0, 0);
}

// Phase 1: row-normalize z, scale x32, cast fp8 e4m3 -> zn8; zero rowsum.
// One wave per row; grid = N/4 blocks of 256 threads (4 waves).
__global__ __launch_bounds__(256) void k_normalize(const float* __restrict__ z,
                                                   unsigned char* __restrict__ zn8,
                                                   float* __restrict__ rowsum) {
  const int gt = blockIdx.x * 256 + threadIdx.x;
  if (gt < N) rowsum[gt] = 0.0f;
  const int row = gt >> 6;
  const int l = threadIdx.x & 63;
  const float4* zr = (const float4*)(z + (size_t)row * D);
  float4 v[4];
  float ss = 0.f;
#pragma unroll
  for (int j = 0; j < 4; ++j) {
    v[j] = zr[l + 64 * j];  // coalesced: lane-consecutive 16B
    ss += v[j].x * v[j].x + v[j].y * v[j].y + v[j].z * v[j].z + v[j].w * v[j].w;
  }
#pragma unroll
  for (int off = 32; off > 0; off >>= 1) ss += __shfl_xor(ss, off, 64);
  const float sc = 32.0f / fmaxf(sqrtf(ss), 1e-8f);  // e4m3 range; undone by ACC_SCALE
  int* orow = (int*)(zn8 + (size_t)row * D);
#pragma unroll
  for (int j = 0; j < 4; ++j) {
    int p = __builtin_amdgcn_cvt_pk_fp8_f32(v[j].x * sc, v[j].y * sc, 0, false);
    p = __builtin_amdgcn_cvt_pk_fp8_f32(v[j].z * sc, v[j].w * sc, p, true);
    orow[l + 64 * j] = p;  // coalesced 4B stores, same element order as loads
  }
}

// Phase 2: 128x128 lower-triangle tile per block, 512 threads (8 waves, 4x2).
// fp8 BK=128: per stage A 16KB + B 16KB; double-buffered = 64KB dynamic LDS
// -> 2 blocks/CU.
__global__ __launch_bounds__(512, 4) void k_tile(const unsigned char* __restrict__ zn8,
                                                 float* __restrict__ rowsum,
                                                 float* __restrict__ pos) {
  extern __shared__ __align__(16) char smem[];  // 65536
  const int tid = threadIdx.x;
  const int w = tid >> 6, l = tid & 63;

  // decode blockIdx -> lower-triangle (tr, tc), tr >= tc, over 64x64 tile grid
  const int b = blockIdx.x;
  int tr = (int)((sqrtf(8.0f * (float)b + 1.0f) - 1.0f) * 0.5f);
  if (tr * (tr + 1) / 2 > b) --tr;
  if ((tr + 1) * (tr + 2) / 2 <= b) ++tr;
  const int tc = b - tr * (tr + 1) / 2;
  const bool diag = (tr == tc);

  const int wr = w >> 1, wc = w & 1;  // wave tile: 32 rows x 64 cols
  const int m = l & 15, kg = l >> 4;
  const int rowA0 = tr * 128, colB0 = tc * 128;

  f32x4 acc[2][4] = {};

  // staging: per matrix per stage 1024 slots x 16B (128 rows x 8 chunks of 16B).
  // phys slot s -> row s>>3; phys chunk s&7 holds logical chunk (s&7)^(row&7).
  int srow[2], scol[2];
#pragma unroll
  for (int j = 0; j < 2; ++j) {
    int s = j * 512 + tid;
    int r = s >> 3;
    srow[j] = r;
    scol[j] = (s & 7) ^ (r & 7);
  }

  // fragment reads: logical chunks kg, kg+4 (K-permuted; A/B identical)
  const int csw0 = (kg ^ (m & 7)) * 16;
  const int csw1 = ((kg + 4) ^ (m & 7)) * 16;

  // prologue: stage kt=0 into buffer 0
  {
    char* ab = smem;
    char* bb = smem + 16384;
#pragma unroll
    for (int j = 0; j < 2; ++j) {
      const int s = j * 512 + tid;
      gload16((const char*)zn8 + ((size_t)(rowA0 + srow[j]) * D + scol[j] * 16), ab + s * 16);
    }
    if (!diag) {
#pragma unroll
      for (int j = 0; j < 2; ++j) {
        const int s = j * 512 + tid;
        gload16((const char*)zn8 + ((size_t)(colB0 + srow[j]) * D + scol[j] * 16), bb + s * 16);
      }
    }
  }
  __syncthreads();

  for (int kt = 0; kt < 8; ++kt) {
    if (kt < 7) {  // async prefetch kt+1 into other buffer; overlaps MFMA below
      const size_t kb = (size_t)(kt + 1) * 128;
      char* ab = smem + ((kt + 1) & 1) * 32768;
#pragma unroll
      for (int j = 0; j < 2; ++j) {
        const int s = j * 512 + tid;
        gload16((const char*)zn8 + ((size_t)(rowA0 + srow[j]) * D + kb + scol[j] * 16), ab + s * 16);
      }
      if (!diag) {
        char* bb = ab + 16384;
#pragma unroll
        for (int j = 0; j < 2; ++j) {
          const int s = j * 512 + tid;
          gload16((const char*)zn8 + ((size_t)(colB0 + srow[j]) * D + kb + scol[j] * 16), bb + s * 16);
        }
      }
    }
    const char* ab = smem + (kt & 1) * 32768;
    const char* bb = diag ? ab : (ab + 16384);

    lx2 a0[2], a1[2];
#pragma unroll
    for (int mt = 0; mt < 2; ++mt) {
      const char* rp = ab + (wr * 32 + mt * 16 + m) * 128;
      a0[mt] = *(const lx2*)(rp + csw0);
      a1[mt] = *(const lx2*)(rp + csw1);
    }
#pragma unroll
    for (int nt = 0; nt < 4; ++nt) {
      const char* rp = bb + (wc * 64 + nt * 16 + m) * 128;
      const lx2 b0 = *(const lx2*)(rp + csw0);
      const lx2 b1 = *(const lx2*)(rp + csw1);
#pragma unroll
      for (int mt = 0; mt < 2; ++mt) {
        acc[mt][nt] = __builtin_amdgcn_mfma_f32_16x16x32_fp8_fp8(a0[mt].x, b0.x, acc[mt][nt], 0, 0, 0);
        acc[mt][nt] = __builtin_amdgcn_mfma_f32_16x16x32_fp8_fp8(a0[mt].y, b0.y, acc[mt][nt], 0, 0, 0);
        acc[mt][nt] = __builtin_amdgcn_mfma_f32_16x16x32_fp8_fp8(a1[mt].x, b1.x, acc[mt][nt], 0, 0, 0);
        acc[mt][nt] = __builtin_amdgcn_mfma_f32_16x16x32_fp8_fp8(a1[mt].y, b1.y, acc[mt][nt], 0, 0, 0);
      }
    }
    __syncthreads();  // drains prefetch (vmcnt) + guards buffer reuse
  }

  // Epilogue. C/D layout: col=l&15, row=(l>>4)*4+reg.
  const int quad = l >> 4;
  const int col = l & 15;
  float cs[4] = {0.f, 0.f, 0.f, 0.f};
#pragma unroll
  for (int mt = 0; mt < 2; ++mt) {
    float rs[4] = {0.f, 0.f, 0.f, 0.f};
#pragma unroll
    for (int nt = 0; nt < 4; ++nt) {
      const int gcol = colB0 + wc * 64 + nt * 16 + col;
#pragma unroll
      for (int r = 0; r < 4; ++r) {
        const int grow = rowA0 + wr * 32 + mt * 16 + quad * 4 + r;
        const float t = acc[mt][nt][r] * ACC_SCALE;
        if (gcol == (grow ^ (N / 2))) {  // pos pair; never in diag tiles
          pos[grow] = t;
          pos[gcol] = t;  // S symmetric
        }
        const float e = (gcol == grow) ? 0.0f : __expf(t - INV_T);
        rs[r] += e;
        cs[nt] += e;
      }
    }
#pragma unroll
    for (int off = 1; off < 16; off <<= 1) {
#pragma unroll
      for (int r = 0; r < 4; ++r) rs[r] += __shfl_xor(rs[r], off, 64);
    }
    if (col == 0) {
#pragma unroll
      for (int r = 0; r < 4; ++r)
        atomicAdd(&rowsum[rowA0 + wr * 32 + mt * 16 + quad * 4 + r], rs[r]);
    }
  }
  if (!diag) {  // col sums = row-sums for block tc rows (symmetry)
#pragma unroll
    for (int nt = 0; nt < 4; ++nt) {
      cs[nt] += __shfl_xor(cs[nt], 16, 64);
      cs[nt] += __shfl_xor(cs[nt], 32, 64);
    }
    if (l < 16) {
#pragma unroll
      for (int nt = 0; nt < 4; ++nt)
        atomicAdd(&rowsum[colB0 + wc * 64 + nt * 16 + l], cs[nt]);
    }
  }
}

// Phase 3: single block: out = mean(-pos + C + log(rowsum)).
__global__ __launch_bounds__(1024) void k_final(const float* __restrict__ rowsum,
                                                const float* __restrict__ pos,
                                                float* __restrict__ out) {
  const int t = threadIdx.x;
  float s = 0.f;
  for (int i = t; i < N; i += 1024) s += INV_T + __logf(rowsum[i]) - pos[i];
#pragma unroll
  for (int off = 32; off > 0; off >>= 1) s += __shfl_down(s, off, 64);
  __shared__ float red[16];
  if ((t & 63) == 0) red[t >> 6] = s;
  __syncthreads();
  if (t == 0) {
    float tot = 0.f;
#pragma unroll
    for (int j = 0; j < 16; ++j) tot += red[j];
    out[0] = tot * (1.0f / N);
  }
}

extern "C" void kernel_launch(void* const* d_in, const int* in_sizes, int n_in,
                              void* d_out, int out_size, void* d_ws, size_t ws_size,
                              hipStream_t stream) {
  const float* z = (const float*)d_in[0];
  float* out = (float*)d_out;
  char* ws = (char*)d_ws;
  unsigned char* zn8 = (unsigned char*)ws;                    // 8 MiB fp8
  float* rowsum = (float*)(ws + (size_t)N * D);               // 32 KiB
  float* pos = (float*)(ws + (size_t)N * D + (size_t)N * 4);  // 32 KiB

  static bool attr_set = false;
  if (!attr_set) {  // host-side attribute, idempotent, not a stream op
    hipFuncSetAttribute((const void*)k_tile,
                        hipFuncAttributeMaxDynamicSharedMemorySize, 65536);
    attr_set = true;
  }

  k_normalize<<<N / 4, 256, 0, stream>>>(z, zn8, rowsum);
  k_tile<<<NTILES, 512, 65536, stream>>>(zn8, rowsum, pos);
  k_final<<<1, 1024, 0, stream>>>(rowsum, pos, out);
}

// Round 6
// 157.753 us; speedup vs baseline: 1.3526x; 1.0266x over previous
//
#include <hip/hip_runtime.h>
#include <hip/hip_bf16.h>

// ContrastiveLoss: z (8192x1024 fp32) -> scalar
//   zn = z / max(||z||,eps); S = zn@zn^T; diag=MASK; /T; nll = -S[i,i^4096] + lse(S[i,:]); mean
// R13: R7's proven 256x256 fp8 tile body, repacked to kill the 3-round
// quantization (528 blocks / 256 single-block CUs = 23% idle).
// Work units: 32 diag tiles FULL (blocks 0..31, ~2x cost, scheduled first;
// no B staging) + 496 off-diag tiles split into 2 N-halves of 256x128
// (blocks 32..1023; consecutive blocks share the A panel -> L2 locality).
// Makespan model: 256T = 992*12.8 + 32*24.7 -> T ~= 53us (vs 74.2).
// Halves keep MFMA-dominance (LDS-pipe ratio 61% vs R12's fatal 92% at 128^2).
// Inner loop/swizzle/K-permuted b128 fragments/epilogue identical to R7
// (0-conflict measured, absmax 0.0). LDS = 2 x (A 32KB + B 16KB) = 96KB.
// R9/R8 lesson: spill signature = WRITE_SIZE >> 10MB; watch VGPR count.
// R10/R11 lessons: keep __syncthreads-per-stage schedule; keep 3-kernel chain
// (the ~71us total-minus-k_tile gap is fixed harness overhead).

#define N 8192
#define D 1024
#define INV_T 14.285714285714286f
#define NBLK 1024  // 32 diag fulls + 992 off-diag halves
#define ACC_SCALE (INV_T / 1024.0f)  // undo fp8 x32 scaling on both operands

typedef float f32x4 __attribute__((ext_vector_type(4)));
typedef long lx2 __attribute__((ext_vector_type(2)));

__device__ inline void gload16(const void* g, void* l) {
  __builtin_amdgcn_global_load_lds(
      (const __attribute__((address_space(1))) void*)g,
      (__attribute__((address_space(3))) void*)l, 16, 0, 0);
}

// Phase 1: row-normalize z, scale x32, cast fp8 e4m3 -> zn8; zero rowsum.
__global__ __launch_bounds__(256) void k_normalize(const float* __restrict__ z,
                                                   unsigned char* __restrict__ zn8,
                                                   float* __restrict__ rowsum) {
  const int gt = blockIdx.x * 256 + threadIdx.x;
  if (gt < N) rowsum[gt] = 0.0f;
  const int row = gt >> 6;
  const int l = threadIdx.x & 63;
  const float4* zr = (const float4*)(z + (size_t)row * D);
  float4 v[4];
  float ss = 0.f;
#pragma unroll
  for (int j = 0; j < 4; ++j) {
    v[j] = zr[l + 64 * j];  // coalesced: lane-consecutive 16B
    ss += v[j].x * v[j].x + v[j].y * v[j].y + v[j].z * v[j].z + v[j].w * v[j].w;
  }
#pragma unroll
  for (int off = 32; off > 0; off >>= 1) ss += __shfl_xor(ss, off, 64);
  const float sc = 32.0f / fmaxf(sqrtf(ss), 1e-8f);  // e4m3 range; undone by ACC_SCALE
  int* orow = (int*)(zn8 + (size_t)row * D);
#pragma unroll
  for (int j = 0; j < 4; ++j) {
    int p = __builtin_amdgcn_cvt_pk_fp8_f32(v[j].x * sc, v[j].y * sc, 0, false);
    p = __builtin_amdgcn_cvt_pk_fp8_f32(v[j].z * sc, v[j].w * sc, p, true);
    orow[l + 64 * j] = p;  // coalesced 4B stores, same element order as loads
  }
}

// Phase 2: blocks 0..31 = full 256x256 diag tiles; blocks 32..1023 = 256x128
// off-diag N-halves. 512 threads (8 waves). LDS 2 x 48KB = 96KB dynamic.
__global__ __launch_bounds__(512, 2) void k_tile(const unsigned char* __restrict__ zn8,
                                                 float* __restrict__ rowsum,
                                                 float* __restrict__ pos) {
  extern __shared__ __align__(16) char smem[];  // 98304
  const int tid = threadIdx.x;
  const int w = tid >> 6, l = tid & 63;
  const int wr = w >> 1, wc = w & 1;
  const int m = l & 15, kg = l >> 4;
  const int quad = l >> 4, col = l & 15;

  // staging map (A panel, 256 rows x 8 chunks = 2048 slots x 16B):
  // phys slot s -> row s>>3; phys chunk s&7 holds logical chunk (s&7)^(row&7).
  int srow[4], scol[4];
#pragma unroll
  for (int j = 0; j < 4; ++j) {
    int s = j * 512 + tid;
    int r = s >> 3;
    srow[j] = r;
    scol[j] = (s & 7) ^ (r & 7);
  }
  // fragment reads: logical chunks kg, kg+4 (K-permuted; A/B identical)
  const int csw0 = (kg ^ (m & 7)) * 16;
  const int csw1 = ((kg + 4) ^ (m & 7)) * 16;

  const int b = blockIdx.x;

  if (b < 32) {
    // ---------------- DIAG: full 256x256 tile, B == A panel ----------------
    const int rowA0 = b * 256, colB0 = b * 256;
    f32x4 acc[4][8] = {};

    {  // prologue: stage kt=0 A panel into buffer 0
      char* ab = smem;
#pragma unroll
      for (int j = 0; j < 4; ++j) {
        const int s = j * 512 + tid;
        gload16((const char*)zn8 + ((size_t)(rowA0 + srow[j]) * D + scol[j] * 16), ab + s * 16);
      }
    }
    __syncthreads();

    for (int kt = 0; kt < 8; ++kt) {
      if (kt < 7) {
        const size_t kb = (size_t)(kt + 1) * 128;
        char* ab = smem + ((kt + 1) & 1) * 49152;
#pragma unroll
        for (int j = 0; j < 4; ++j) {
          const int s = j * 512 + tid;
          gload16((const char*)zn8 + ((size_t)(rowA0 + srow[j]) * D + kb + scol[j] * 16), ab + s * 16);
        }
      }
      const char* ab = smem + (kt & 1) * 49152;

      lx2 a0[4], a1[4];
#pragma unroll
      for (int mt = 0; mt < 4; ++mt) {
        const char* rp = ab + (wr * 64 + mt * 16 + m) * 128;
        a0[mt] = *(const lx2*)(rp + csw0);
        a1[mt] = *(const lx2*)(rp + csw1);
      }
#pragma unroll
      for (int nt = 0; nt < 8; ++nt) {
        const char* rp = ab + (wc * 128 + nt * 16 + m) * 128;
        const lx2 b0 = *(const lx2*)(rp + csw0);
        const lx2 b1 = *(const lx2*)(rp + csw1);
#pragma unroll
        for (int mt = 0; mt < 4; ++mt) {
          acc[mt][nt] = __builtin_amdgcn_mfma_f32_16x16x32_fp8_fp8(a0[mt].x, b0.x, acc[mt][nt], 0, 0, 0);
          acc[mt][nt] = __builtin_amdgcn_mfma_f32_16x16x32_fp8_fp8(a0[mt].y, b0.y, acc[mt][nt], 0, 0, 0);
          acc[mt][nt] = __builtin_amdgcn_mfma_f32_16x16x32_fp8_fp8(a1[mt].x, b1.x, acc[mt][nt], 0, 0, 0);
          acc[mt][nt] = __builtin_amdgcn_mfma_f32_16x16x32_fp8_fp8(a1[mt].y, b1.y, acc[mt][nt], 0, 0, 0);
        }
      }
      __syncthreads();
    }

    // epilogue (diag: mask gcol==grow, no pos pairs, no symmetric col-sum)
#pragma unroll
    for (int mt = 0; mt < 4; ++mt) {
      float rs[4] = {0.f, 0.f, 0.f, 0.f};
#pragma unroll
      for (int nt = 0; nt < 8; ++nt) {
        const int gcol = colB0 + wc * 128 + nt * 16 + col;
#pragma unroll
        for (int r = 0; r < 4; ++r) {
          const int grow = rowA0 + wr * 64 + mt * 16 + quad * 4 + r;
          const float t = acc[mt][nt][r] * ACC_SCALE;
          rs[r] += (gcol == grow) ? 0.0f : __expf(t - INV_T);
        }
      }
#pragma unroll
      for (int off = 1; off < 16; off <<= 1) {
#pragma unroll
        for (int r = 0; r < 4; ++r) rs[r] += __shfl_xor(rs[r], off, 64);
      }
      if (col == 0) {
#pragma unroll
        for (int r = 0; r < 4; ++r)
          atomicAdd(&rowsum[rowA0 + wr * 64 + mt * 16 + quad * 4 + r], rs[r]);
      }
    }
  } else {
    // ------------- OFF-DIAG N-HALF: 256 rows x 128 cols ---------------------
    int p = b - 32;
    const int h = p & 1;
    p >>= 1;
    // strict lower-triangle decode: tr in 1..31, tc < tr
    int tr = (int)((1.0f + sqrtf(8.0f * (float)p + 1.0f)) * 0.5f);
    if (tr * (tr - 1) / 2 > p) --tr;
    if (tr * (tr + 1) / 2 <= p) ++tr;
    const int tc = p - tr * (tr - 1) / 2;
    const int rowA0 = tr * 256, colB0 = tc * 256 + h * 128;

    f32x4 acc[4][4] = {};

    {  // prologue: A panel (4 loads) + B half-panel (2 loads) into buffer 0
      char* ab = smem;
      char* bb = smem + 32768;
#pragma unroll
      for (int j = 0; j < 4; ++j) {
        const int s = j * 512 + tid;
        gload16((const char*)zn8 + ((size_t)(rowA0 + srow[j]) * D + scol[j] * 16), ab + s * 16);
      }
#pragma unroll
      for (int j = 0; j < 2; ++j) {
        const int s = j * 512 + tid;
        gload16((const char*)zn8 + ((size_t)(colB0 + srow[j]) * D + scol[j] * 16), bb + s * 16);
      }
    }
    __syncthreads();

    for (int kt = 0; kt < 8; ++kt) {
      if (kt < 7) {
        const size_t kb = (size_t)(kt + 1) * 128;
        char* ab = smem + ((kt + 1) & 1) * 49152;
        char* bb = ab + 32768;
#pragma unroll
        for (int j = 0; j < 4; ++j) {
          const int s = j * 512 + tid;
          gload16((const char*)zn8 + ((size_t)(rowA0 + srow[j]) * D + kb + scol[j] * 16), ab + s * 16);
        }
#pragma unroll
        for (int j = 0; j < 2; ++j) {
          const int s = j * 512 + tid;
          gload16((const char*)zn8 + ((size_t)(colB0 + srow[j]) * D + kb + scol[j] * 16), bb + s * 16);
        }
      }
      const char* ab = smem + (kt & 1) * 49152;
      const char* bb = ab + 32768;

      lx2 a0[4], a1[4];
#pragma unroll
      for (int mt = 0; mt < 4; ++mt) {
        const char* rp = ab + (wr * 64 + mt * 16 + m) * 128;
        a0[mt] = *(const lx2*)(rp + csw0);
        a1[mt] = *(const lx2*)(rp + csw1);
      }
#pragma unroll
      for (int nt = 0; nt < 4; ++nt) {
        const char* rp = bb + (wc * 64 + nt * 16 + m) * 128;
        const lx2 b0 = *(const lx2*)(rp + csw0);
        const lx2 b1 = *(const lx2*)(rp + csw1);
#pragma unroll
        for (int mt = 0; mt < 4; ++mt) {
          acc[mt][nt] = __builtin_amdgcn_mfma_f32_16x16x32_fp8_fp8(a0[mt].x, b0.x, acc[mt][nt], 0, 0, 0);
          acc[mt][nt] = __builtin_amdgcn_mfma_f32_16x16x32_fp8_fp8(a0[mt].y, b0.y, acc[mt][nt], 0, 0, 0);
          acc[mt][nt] = __builtin_amdgcn_mfma_f32_16x16x32_fp8_fp8(a1[mt].x, b1.x, acc[mt][nt], 0, 0, 0);
          acc[mt][nt] = __builtin_amdgcn_mfma_f32_16x16x32_fp8_fp8(a1[mt].y, b1.y, acc[mt][nt], 0, 0, 0);
        }
      }
      __syncthreads();
    }

    // epilogue (off-diag: pos pairs possible, symmetric col-sum)
    float cs[4] = {0.f, 0.f, 0.f, 0.f};
#pragma unroll
    for (int mt = 0; mt < 4; ++mt) {
      float rs[4] = {0.f, 0.f, 0.f, 0.f};
#pragma unroll
      for (int nt = 0; nt < 4; ++nt) {
        const int gcol = colB0 + wc * 64 + nt * 16 + col;
#pragma unroll
        for (int r = 0; r < 4; ++r) {
          const int grow = rowA0 + wr * 64 + mt * 16 + quad * 4 + r;
          const float t = acc[mt][nt][r] * ACC_SCALE;
          if (gcol == (grow ^ (N / 2))) {  // pos pair
            pos[grow] = t;
            pos[gcol] = t;  // S symmetric
          }
          const float e = __expf(t - INV_T);  // gcol != grow always off-diag
          rs[r] += e;
          cs[nt] += e;
        }
      }
#pragma unroll
      for (int off = 1; off < 16; off <<= 1) {
#pragma unroll
        for (int r = 0; r < 4; ++r) rs[r] += __shfl_xor(rs[r], off, 64);
      }
      if (col == 0) {
#pragma unroll
        for (int r = 0; r < 4; ++r)
          atomicAdd(&rowsum[rowA0 + wr * 64 + mt * 16 + quad * 4 + r], rs[r]);
      }
    }
#pragma unroll
    for (int nt = 0; nt < 4; ++nt) {
      cs[nt] += __shfl_xor(cs[nt], 16, 64);
      cs[nt] += __shfl_xor(cs[nt], 32, 64);
    }
    if (l < 16) {
#pragma unroll
      for (int nt = 0; nt < 4; ++nt)
        atomicAdd(&rowsum[colB0 + wc * 64 + nt * 16 + l], cs[nt]);
    }
  }
}

// Phase 3: single block: out = mean(-pos + C + log(rowsum)).
__global__ __launch_bounds__(1024) void k_final(const float* __restrict__ rowsum,
                                                const float* __restrict__ pos,
                                                float* __restrict__ out) {
  const int t = threadIdx.x;
  float s = 0.f;
  for (int i = t; i < N; i += 1024) s += INV_T + __logf(rowsum[i]) - pos[i];
#pragma unroll
  for (int off = 32; off > 0; off >>= 1) s += __shfl_down(s, off, 64);
  __shared__ float red[16];
  if ((t & 63) == 0) red[t >> 6] = s;
  __syncthreads();
  if (t == 0) {
    float tot = 0.f;
#pragma unroll
    for (int j = 0; j < 16; ++j) tot += red[j];
    out[0] = tot * (1.0f / N);
  }
}

extern "C" void kernel_launch(void* const* d_in, const int* in_sizes, int n_in,
                              void* d_out, int out_size, void* d_ws, size_t ws_size,
                              hipStream_t stream) {
  const float* z = (const float*)d_in[0];
  float* out = (float*)d_out;
  char* ws = (char*)d_ws;
  unsigned char* zn8 = (unsigned char*)ws;                    // 8 MiB fp8
  float* rowsum = (float*)(ws + (size_t)N * D);               // 32 KiB
  float* pos = (float*)(ws + (size_t)N * D + (size_t)N * 4);  // 32 KiB

  static bool attr_set = false;
  if (!attr_set) {  // host-side attribute, idempotent, not a stream op
    hipFuncSetAttribute((const void*)k_tile,
                        hipFuncAttributeMaxDynamicSharedMemorySize, 98304);
    attr_set = true;
  }

  k_normalize<<<N / 4, 256, 0, stream>>>(z, zn8, rowsum);
  k_tile<<<NBLK, 512, 98304, stream>>>(zn8, rowsum, pos);
  k_final<<<1, 1024, 0, stream>>>(rowsum, pos, out);
}